// Round 3
// baseline (83.980 us; speedup 1.0000x reference)
//
#include <hip/hip_runtime.h>

#define N_NODES 1024
#define B_SZ 64
#define F_IN 10
#define DIM 64
#define TOPK 20
#define BN_TOT (B_SZ * N_NODES)   // 65536

#define GEMM_BLKS 256            // 16x16 tiles of 64x64
#define PREP_BLKS 256            // 1024 nodes / 4 per block
#define HSCAL_BLKS 4096          // 65536 nodes / 16 per block

// ---- Kernel 1 (k_build): gemm_g + prep + hscal fused via block ranges ----
__global__ __launch_bounds__(256) void k_build(
    const float* __restrict__ data, const float* __restrict__ emb,
    const float* __restrict__ W_lin,
    const float* __restrict__ att_i, const float* __restrict__ att_j,
    const float* __restrict__ att_em_i, const float* __restrict__ att_em_j,
    const float* __restrict__ gnn_bias,
    const float* __restrict__ g1, const float* __restrict__ b1,
    const float* __restrict__ m1, const float* __restrict__ v1,
    const float* __restrict__ g2, const float* __restrict__ b2,
    const float* __restrict__ m2, const float* __restrict__ v2,
    float* __restrict__ g, float* __restrict__ h,
    float* __restrict__ dd, float* __restrict__ ss,
    float* __restrict__ edi, float* __restrict__ esi, float* __restrict__ nrm,
    float4* __restrict__ bnp) {
    const int bid = blockIdx.x;
    const int t = threadIdx.x;
    const int lane = t & 63, w = t >> 6;

    if (bid < GEMM_BLKS) {
        // ---- G = emb @ emb^T, 64x64 tile ----
        __shared__ float As[64][65];
        __shared__ float Bs[64][65];
        const int r0 = (bid >> 4) * 64, c0 = (bid & 15) * 64;
#pragma unroll
        for (int k = 0; k < 16; ++k) {
            int idx = t + k * 256;
            int rr = idx >> 6, cc = idx & 63;
            As[rr][cc] = emb[(r0 + rr) * DIM + cc];
            Bs[rr][cc] = emb[(c0 + rr) * DIM + cc];
        }
        __syncthreads();
        const int tx = t & 15, ty = t >> 4;
        float acc[4][4] = {};
#pragma unroll 8
        for (int d = 0; d < 64; ++d) {
            float a[4], b[4];
#pragma unroll
            for (int ii = 0; ii < 4; ++ii) a[ii] = As[ty * 4 + ii][d];
#pragma unroll
            for (int jj = 0; jj < 4; ++jj) b[jj] = Bs[tx * 4 + jj][d];
#pragma unroll
            for (int ii = 0; ii < 4; ++ii)
#pragma unroll
                for (int jj = 0; jj < 4; ++jj) acc[ii][jj] += a[ii] * b[jj];
        }
#pragma unroll
        for (int ii = 0; ii < 4; ++ii)
#pragma unroll
            for (int jj = 0; jj < 4; ++jj)
                g[(r0 + ty * 4 + ii) * N_NODES + (c0 + tx * 4 + jj)] = acc[ii][jj];
        return;
    }

    if (bid < GEMM_BLKS + PREP_BLKS) {
        // ---- prep: per-node emb scalars + norm; first block folds BN params ----
        const int node = (bid - GEMM_BLKS) * 4 + w;
        float e = emb[node * DIM + lane];
        float t1 = e * att_em_i[lane];
        float t2 = e * att_em_j[lane];
        float t3 = e * e;
#pragma unroll
        for (int m = 32; m >= 1; m >>= 1) {
            t1 += __shfl_xor(t1, m, 64);
            t2 += __shfl_xor(t2, m, 64);
            t3 += __shfl_xor(t3, m, 64);
        }
        if (lane == 0) { edi[node] = t1; esi[node] = t2; nrm[node] = sqrtf(t3); }
        if (bid == GEMM_BLKS && t < DIM) {
            float a1 = g1[t] * rsqrtf(v1[t] + 1e-5f);
            float c1 = (gnn_bias[t] - m1[t]) * a1 + b1[t];
            float a2 = g2[t] * rsqrtf(v2[t] + 1e-5f);
            float c2 = b2[t] - m2[t] * a2;
            bnp[t] = make_float4(a1, c1, a2, c2);
        }
        return;
    }

    // ---- hscal: h = x @ W_lin + per-node attention scalars; 16 nodes/block ----
    {
        const int base = (bid - GEMM_BLKS - PREP_BLKS) * 16 + w * 4;
        float wl[F_IN];
#pragma unroll
        for (int f = 0; f < F_IN; ++f) wl[f] = W_lin[f * DIM + lane];
        const float ai = att_i[lane], aj = att_j[lane];
#pragma unroll
        for (int r = 0; r < 4; ++r) {
            const int node = base + r;
            const float* dp = data + node * F_IN;
            float hv = 0.f;
#pragma unroll
            for (int f = 0; f < F_IN; ++f) hv = fmaf(dp[f], wl[f], hv);
            h[node * DIM + lane] = hv;
            float s1 = hv * ai;
            float s2 = hv * aj;
#pragma unroll
            for (int m = 32; m >= 1; m >>= 1) {
                s1 += __shfl_xor(s1, m, 64);
                s2 += __shfl_xor(s2, m, 64);
            }
            if (lane == 0) { dd[node] = s1; ss[node] = s2; }
        }
    }
}

// ---- Kernel 2 (k_topk): per-wave top-20 (no barriers) + single-wave merge ----
__global__ __launch_bounds__(256) void k_topk(const float* __restrict__ g,
                                              const float* __restrict__ nrm,
                                              int* __restrict__ tk) {
    __shared__ float cv[4][20];
    __shared__ int ci[4][20];
    const int i = blockIdx.x;
    const int t = threadIdx.x;
    const int lane = t & 63, w = t >> 6;
    const float ni = nrm[i];
    float4 gv = ((const float4*)(g + (size_t)i * N_NODES))[t];
    float4 nv = ((const float4*)nrm)[t];
    float v[4];
    v[0] = gv.x / (ni * nv.x);
    v[1] = gv.y / (ni * nv.y);
    v[2] = gv.z / (ni * nv.z);
    v[3] = gv.w / (ni * nv.w);
    // phase 1: each wave selects top-20 of its 256 columns (cols 4t..4t+3)
    for (int it = 0; it < TOPK; ++it) {
        float bv = v[0];
        int bq = 0;
#pragma unroll
        for (int q = 1; q < 4; ++q)
            if (v[q] > bv) { bv = v[q]; bq = q; }
        int bidx = t * 4 + bq;
#pragma unroll
        for (int m = 32; m >= 1; m >>= 1) {
            float ov = __shfl_xor(bv, m, 64);
            int oi = __shfl_xor(bidx, m, 64);
            if (ov > bv || (ov == bv && oi < bidx)) { bv = ov; bidx = oi; }
        }
        if (lane == 0) { cv[w][it] = bv; ci[w][it] = bidx; }
        if ((bidx >> 2) == t) v[bidx & 3] = -3.0e38f;
    }
    __syncthreads();
    // phase 2: wave 0 merges 80 candidates -> global top-20
    if (w == 0) {
        float mv[4];
        int mi[4];
#pragma unroll
        for (int q = 0; q < 4; ++q) {
            if (lane < TOPK) { mv[q] = cv[q][lane]; mi[q] = ci[q][lane]; }
            else { mv[q] = -3.0e38f; mi[q] = 0x7fffffff; }
        }
        for (int it = 0; it < TOPK; ++it) {
            float bv = mv[0];
            int bq = 0;
#pragma unroll
            for (int q = 1; q < 4; ++q)
                if (mv[q] > bv || (mv[q] == bv && mi[q] < mi[bq])) { bv = mv[q]; bq = q; }
            int bidx = mi[bq];
#pragma unroll
            for (int m = 32; m >= 1; m >>= 1) {
                float ov = __shfl_xor(bv, m, 64);
                int oi = __shfl_xor(bidx, m, 64);
                if (ov > bv || (ov == bv && oi < bidx)) { bv = ov; bidx = oi; }
            }
            if (lane == 0) tk[i * TOPK + it] = bidx;
#pragma unroll
            for (int q = 0; q < 4; ++q)
                if (mi[q] == bidx) mv[q] = -3.0e38f;
        }
    }
}

// ---- Kernel 3 (k_main): softmax + aggregate + folded BN/head ----
__global__ __launch_bounds__(256) void k_main(
    const float* __restrict__ h, const float* __restrict__ emb,
    const float* __restrict__ dd, const float* __restrict__ ss,
    const float* __restrict__ edi, const float* __restrict__ esi,
    const int* __restrict__ tk, const float4* __restrict__ bnp,
    const float* __restrict__ outW, const float* __restrict__ outB,
    float* __restrict__ out) {
    __shared__ int jbuf[4][24];
    __shared__ float abuf[4][24];
    const int bid = blockIdx.x;
    const int nb = (bid & 7) * 2048 + (bid >> 3);   // XCD swizzle: 8 batches per XCD
    const int w = threadIdx.x >> 6, lane = threadIdx.x & 63;
    const int node = nb * 4 + w;
    const int i = node & (N_NODES - 1);
    const int bbase = node & ~(N_NODES - 1);

    int j = i;
    if (lane < TOPK) j = tk[i * TOPK + lane];
    if (lane <= TOPK) jbuf[w][lane] = j;
    __builtin_amdgcn_wave_barrier();
    int4 jj4[5];
#pragma unroll
    for (int q = 0; q < 5; ++q) jj4[q] = ((int4*)jbuf[w])[q];
    int j20 = jbuf[w][20];

    // issue all 21 gathers up front (independent loads)
    const float* hb = h + (size_t)bbase * DIM + lane;
    float hv[21];
#pragma unroll
    for (int q = 0; q < 5; ++q) {
        hv[4 * q + 0] = hb[jj4[q].x * DIM];
        hv[4 * q + 1] = hb[jj4[q].y * DIM];
        hv[4 * q + 2] = hb[jj4[q].z * DIM];
        hv[4 * q + 3] = hb[jj4[q].w * DIM];
    }
    hv[20] = hb[j20 * DIM];

    // softmax over <=21 logits while loads are in flight
    const bool masked = (lane < TOPK) && (j == i);
    const float dde = dd[node] + edi[i];
    float lg = -3.0e38f;
    if (lane <= TOPK) {
        float l = dde + ss[bbase + j] + esi[j];
        l = (l > 0.f) ? l : 0.2f * l;
        lg = masked ? -3.0e38f : l;
    }
    float m = lg;
#pragma unroll
    for (int mm = 16; mm >= 1; mm >>= 1) m = fmaxf(m, __shfl_xor(m, mm, 64));
    float ex = (lane <= TOPK && !masked) ? __expf(lg - m) : 0.f;
    float s = ex;
#pragma unroll
    for (int mm = 16; mm >= 1; mm >>= 1) s += __shfl_xor(s, mm, 64);
    const float alpha = ex / s;
    if (lane <= TOPK) abuf[w][lane] = alpha;
    __builtin_amdgcn_wave_barrier();
    float4 aa4[5];
#pragma unroll
    for (int q = 0; q < 5; ++q) aa4[q] = ((float4*)abuf[w])[q];
    float a20 = abuf[w][20];

    float agg = 0.f;
#pragma unroll
    for (int q = 0; q < 5; ++q) {
        agg = fmaf(aa4[q].x, hv[4 * q + 0], agg);
        agg = fmaf(aa4[q].y, hv[4 * q + 1], agg);
        agg = fmaf(aa4[q].z, hv[4 * q + 2], agg);
        agg = fmaf(aa4[q].w, hv[4 * q + 3], agg);
    }
    agg = fmaf(a20, hv[20], agg);

    const float4 p = bnp[lane];
    float x1 = fmaxf(fmaf(agg, p.x, p.y), 0.f);
    float y = x1 * emb[i * DIM + lane];
    float x2 = fmaxf(fmaf(y, p.z, p.w), 0.f);
    float o = x2 * outW[lane];
#pragma unroll
    for (int mm = 32; mm >= 1; mm >>= 1) o += __shfl_xor(o, mm, 64);
    if (lane == 0) out[node] = o + outB[0];
}

extern "C" void kernel_launch(void* const* d_in, const int* in_sizes, int n_in,
                              void* d_out, int out_size, void* d_ws, size_t ws_size,
                              hipStream_t stream) {
    const float* data     = (const float*)d_in[0];
    const float* emb      = (const float*)d_in[1];
    const float* W_lin    = (const float*)d_in[2];
    const float* att_i    = (const float*)d_in[3];
    const float* att_j    = (const float*)d_in[4];
    const float* att_em_i = (const float*)d_in[5];
    const float* att_em_j = (const float*)d_in[6];
    const float* gnn_bias = (const float*)d_in[7];
    const float* g1 = (const float*)d_in[8];
    const float* b1 = (const float*)d_in[9];
    const float* m1 = (const float*)d_in[10];
    const float* v1 = (const float*)d_in[11];
    const float* g2 = (const float*)d_in[12];
    const float* b2 = (const float*)d_in[13];
    const float* m2 = (const float*)d_in[14];
    const float* v2 = (const float*)d_in[15];
    const float* outW = (const float*)d_in[16];
    const float* outB = (const float*)d_in[17];
    float* out = (float*)d_out;

    float* ws = (float*)d_ws;
    float* g     = ws;                          // 1M floats (4 MB)
    float* h     = ws + (1 << 20);              // 4M floats (16 MB)
    float* dd    = h + (size_t)BN_TOT * DIM;    // 65536
    float* ss    = dd + BN_TOT;                 // 65536
    float* edi   = ss + BN_TOT;                 // 1024
    float* esi   = edi + N_NODES;               // 1024
    float* nrm   = esi + N_NODES;               // 1024
    int*   tk    = (int*)(nrm + N_NODES);       // 1024*20 ints
    float4* bnp  = (float4*)(tk + N_NODES * TOPK); // 64 float4

    k_build<<<GEMM_BLKS + PREP_BLKS + HSCAL_BLKS, 256, 0, stream>>>(
        data, emb, W_lin, att_i, att_j, att_em_i, att_em_j, gnn_bias,
        g1, b1, m1, v1, g2, b2, m2, v2,
        g, h, dd, ss, edi, esi, nrm, bnp);
    k_topk<<<N_NODES, 256, 0, stream>>>(g, nrm, tk);
    k_main<<<BN_TOT / 4, 256, 0, stream>>>(h, emb, dd, ss, edi, esi, tk, bnp,
                                           outW, outB, out);
}

// Round 4
// 83.679 us; speedup vs baseline: 1.0036x; 1.0036x over previous
//
#include <hip/hip_runtime.h>

#define N_NODES 1024
#define B_SZ 64
#define F_IN 10
#define DIM 64
#define TOPK 20
#define BN_TOT (B_SZ * N_NODES)   // 65536

#define GEMM_BLKS 256            // 16x16 tiles of 64x64
#define PREP_BLKS 256            // 1024 nodes / 4 per block
#define HSCAL_BLKS 4096          // 65536 nodes / 16 per block

// ---- Kernel 1 (k_build): gemm_g + prep + hscal fused via block ranges ----
__global__ __launch_bounds__(256) void k_build(
    const float* __restrict__ data, const float* __restrict__ emb,
    const float* __restrict__ W_lin,
    const float* __restrict__ att_i, const float* __restrict__ att_j,
    const float* __restrict__ att_em_i, const float* __restrict__ att_em_j,
    const float* __restrict__ gnn_bias,
    const float* __restrict__ g1, const float* __restrict__ b1,
    const float* __restrict__ m1, const float* __restrict__ v1,
    const float* __restrict__ g2, const float* __restrict__ b2,
    const float* __restrict__ m2, const float* __restrict__ v2,
    float* __restrict__ g, float* __restrict__ h,
    float* __restrict__ dd, float* __restrict__ ss,
    float* __restrict__ edi, float* __restrict__ esi, float* __restrict__ nrm,
    float4* __restrict__ bnp) {
    const int bid = blockIdx.x;
    const int t = threadIdx.x;
    const int lane = t & 63, w = t >> 6;

    if (bid < GEMM_BLKS) {
        __shared__ float As[64][65];
        __shared__ float Bs[64][65];
        const int r0 = (bid >> 4) * 64, c0 = (bid & 15) * 64;
#pragma unroll
        for (int k = 0; k < 16; ++k) {
            int idx = t + k * 256;
            int rr = idx >> 6, cc = idx & 63;
            As[rr][cc] = emb[(r0 + rr) * DIM + cc];
            Bs[rr][cc] = emb[(c0 + rr) * DIM + cc];
        }
        __syncthreads();
        const int tx = t & 15, ty = t >> 4;
        float acc[4][4] = {};
#pragma unroll 8
        for (int d = 0; d < 64; ++d) {
            float a[4], b[4];
#pragma unroll
            for (int ii = 0; ii < 4; ++ii) a[ii] = As[ty * 4 + ii][d];
#pragma unroll
            for (int jj = 0; jj < 4; ++jj) b[jj] = Bs[tx * 4 + jj][d];
#pragma unroll
            for (int ii = 0; ii < 4; ++ii)
#pragma unroll
                for (int jj = 0; jj < 4; ++jj) acc[ii][jj] += a[ii] * b[jj];
        }
#pragma unroll
        for (int ii = 0; ii < 4; ++ii)
#pragma unroll
            for (int jj = 0; jj < 4; ++jj)
                g[(r0 + ty * 4 + ii) * N_NODES + (c0 + tx * 4 + jj)] = acc[ii][jj];
        return;
    }

    if (bid < GEMM_BLKS + PREP_BLKS) {
        const int node = (bid - GEMM_BLKS) * 4 + w;
        float e = emb[node * DIM + lane];
        float t1 = e * att_em_i[lane];
        float t2 = e * att_em_j[lane];
        float t3 = e * e;
#pragma unroll
        for (int m = 32; m >= 1; m >>= 1) {
            t1 += __shfl_xor(t1, m, 64);
            t2 += __shfl_xor(t2, m, 64);
            t3 += __shfl_xor(t3, m, 64);
        }
        if (lane == 0) { edi[node] = t1; esi[node] = t2; nrm[node] = sqrtf(t3); }
        if (bid == GEMM_BLKS && t < DIM) {
            float a1 = g1[t] * rsqrtf(v1[t] + 1e-5f);
            float c1 = (gnn_bias[t] - m1[t]) * a1 + b1[t];
            float a2 = g2[t] * rsqrtf(v2[t] + 1e-5f);
            float c2 = b2[t] - m2[t] * a2;
            bnp[t] = make_float4(a1, c1, a2, c2);
        }
        return;
    }

    {
        const int base = (bid - GEMM_BLKS - PREP_BLKS) * 16 + w * 4;
        float wl[F_IN];
#pragma unroll
        for (int f = 0; f < F_IN; ++f) wl[f] = W_lin[f * DIM + lane];
        const float ai = att_i[lane], aj = att_j[lane];
#pragma unroll
        for (int r = 0; r < 4; ++r) {
            const int node = base + r;
            const float* dp = data + node * F_IN;
            float hv = 0.f;
#pragma unroll
            for (int f = 0; f < F_IN; ++f) hv = fmaf(dp[f], wl[f], hv);
            h[node * DIM + lane] = hv;
            float s1 = hv * ai;
            float s2 = hv * aj;
#pragma unroll
            for (int m = 32; m >= 1; m >>= 1) {
                s1 += __shfl_xor(s1, m, 64);
                s2 += __shfl_xor(s2, m, 64);
            }
            if (lane == 0) { dd[node] = s1; ss[node] = s2; }
        }
    }
}

// ---- Kernel 2 (k_topk): per-wave top-20 (no barriers) + single-wave merge ----
__global__ __launch_bounds__(256) void k_topk(const float* __restrict__ g,
                                              const float* __restrict__ nrm,
                                              int* __restrict__ tk) {
    __shared__ float cv[4][20];
    __shared__ int ci[4][20];
    const int i = blockIdx.x;
    const int t = threadIdx.x;
    const int lane = t & 63, w = t >> 6;
    const float ni = nrm[i];
    float4 gv = ((const float4*)(g + (size_t)i * N_NODES))[t];
    float4 nv = ((const float4*)nrm)[t];
    float v[4];
    v[0] = gv.x / (ni * nv.x);
    v[1] = gv.y / (ni * nv.y);
    v[2] = gv.z / (ni * nv.z);
    v[3] = gv.w / (ni * nv.w);
    for (int it = 0; it < TOPK; ++it) {
        float bv = v[0];
        int bq = 0;
#pragma unroll
        for (int q = 1; q < 4; ++q)
            if (v[q] > bv) { bv = v[q]; bq = q; }
        int bidx = t * 4 + bq;
#pragma unroll
        for (int m = 32; m >= 1; m >>= 1) {
            float ov = __shfl_xor(bv, m, 64);
            int oi = __shfl_xor(bidx, m, 64);
            if (ov > bv || (ov == bv && oi < bidx)) { bv = ov; bidx = oi; }
        }
        if (lane == 0) { cv[w][it] = bv; ci[w][it] = bidx; }
        if ((bidx >> 2) == t) v[bidx & 3] = -3.0e38f;
    }
    __syncthreads();
    if (w == 0) {
        float mv[4];
        int mi[4];
#pragma unroll
        for (int q = 0; q < 4; ++q) {
            if (lane < TOPK) { mv[q] = cv[q][lane]; mi[q] = ci[q][lane]; }
            else { mv[q] = -3.0e38f; mi[q] = 0x7fffffff; }
        }
        for (int it = 0; it < TOPK; ++it) {
            float bv = mv[0];
            int bq = 0;
#pragma unroll
            for (int q = 1; q < 4; ++q)
                if (mv[q] > bv || (mv[q] == bv && mi[q] < mi[bq])) { bv = mv[q]; bq = q; }
            int bidx = mi[bq];
#pragma unroll
            for (int m = 32; m >= 1; m >>= 1) {
                float ov = __shfl_xor(bv, m, 64);
                int oi = __shfl_xor(bidx, m, 64);
                if (ov > bv || (ov == bv && oi < bidx)) { bv = ov; bidx = oi; }
            }
            if (lane == 0) tk[i * TOPK + it] = bidx;
#pragma unroll
            for (int q = 0; q < 4; ++q)
                if (mi[q] == bidx) mv[q] = -3.0e38f;
        }
    }
}

// ---- Kernel 3 (k_main): SGPR row indices via readlane; scalar-addressed gathers ----
__global__ __launch_bounds__(256) void k_main(
    const float* __restrict__ h, const float* __restrict__ emb,
    const float* __restrict__ dd, const float* __restrict__ ss,
    const float* __restrict__ edi, const float* __restrict__ esi,
    const int* __restrict__ tk, const float4* __restrict__ bnp,
    const float* __restrict__ outW, const float* __restrict__ outB,
    float* __restrict__ out) {
    const int bid = blockIdx.x;
    const int nb = (bid & 7) * 2048 + (bid >> 3);   // XCD swizzle: 8 batches per XCD
    const int w = threadIdx.x >> 6, lane = threadIdx.x & 63;
    const int node = nb * 4 + w;
    const int i = node & (N_NODES - 1);
    const int bbase = node & ~(N_NODES - 1);

    // per-lane edge source index (lanes 0..19 from tk, others = i)
    int j = i;
    if (lane < TOPK) j = tk[i * TOPK + lane];

    // logit operand gathers FIRST (so softmax doesn't wait on the 21 h-row loads)
    float ssv = 0.f, esv = 0.f;
    if (lane <= TOPK) { ssv = ss[bbase + j]; esv = esi[j]; }
    const float dde = dd[node] + edi[i];           // wave-uniform broadcasts

    // hoist row indices to SGPRs, then issue all 21 h-row gathers
    const float* hb = h + (size_t)bbase * DIM + lane;
    float hv[TOPK + 1];
#pragma unroll
    for (int k = 0; k < TOPK; ++k) {
        int jk = __builtin_amdgcn_readlane(j, k);  // wave-uniform SGPR
        hv[k] = hb[(size_t)jk * DIM];
    }
    hv[TOPK] = hb[(size_t)i * DIM];

    // softmax over <=21 logits (overlaps h-gather latency)
    const bool masked = (lane < TOPK) && (j == i);
    float lg = -3.0e38f;
    if (lane <= TOPK) {
        float l = dde + ssv + esv;
        l = (l > 0.f) ? l : 0.2f * l;              // leaky_relu(0.2)
        lg = masked ? -3.0e38f : l;
    }
    float m = lg;
#pragma unroll
    for (int mm = 16; mm >= 1; mm >>= 1) m = fmaxf(m, __shfl_xor(m, mm, 64));
    float ex = (lane <= TOPK && !masked) ? __expf(lg - m) : 0.f;
    float s = ex;
#pragma unroll
    for (int mm = 16; mm >= 1; mm >>= 1) s += __shfl_xor(s, mm, 64);
    const float alpha = ex / s;                    // valid in lanes 0..20

    // aggregate: alpha_k broadcast via readlane (SGPR operand in the FMA)
    float agg = 0.f;
#pragma unroll
    for (int k = 0; k <= TOPK; ++k) {
        int ab = __builtin_amdgcn_readlane(__float_as_int(alpha), k);
        agg = fmaf(__int_as_float(ab), hv[k], agg);
    }

    const float4 p = bnp[lane];
    float x1 = fmaxf(fmaf(agg, p.x, p.y), 0.f);
    float y = x1 * emb[i * DIM + lane];
    float x2 = fmaxf(fmaf(y, p.z, p.w), 0.f);
    float o = x2 * outW[lane];
#pragma unroll
    for (int mm = 32; mm >= 1; mm >>= 1) o += __shfl_xor(o, mm, 64);
    if (lane == 0) out[node] = o + outB[0];
}

extern "C" void kernel_launch(void* const* d_in, const int* in_sizes, int n_in,
                              void* d_out, int out_size, void* d_ws, size_t ws_size,
                              hipStream_t stream) {
    const float* data     = (const float*)d_in[0];
    const float* emb      = (const float*)d_in[1];
    const float* W_lin    = (const float*)d_in[2];
    const float* att_i    = (const float*)d_in[3];
    const float* att_j    = (const float*)d_in[4];
    const float* att_em_i = (const float*)d_in[5];
    const float* att_em_j = (const float*)d_in[6];
    const float* gnn_bias = (const float*)d_in[7];
    const float* g1 = (const float*)d_in[8];
    const float* b1 = (const float*)d_in[9];
    const float* m1 = (const float*)d_in[10];
    const float* v1 = (const float*)d_in[11];
    const float* g2 = (const float*)d_in[12];
    const float* b2 = (const float*)d_in[13];
    const float* m2 = (const float*)d_in[14];
    const float* v2 = (const float*)d_in[15];
    const float* outW = (const float*)d_in[16];
    const float* outB = (const float*)d_in[17];
    float* out = (float*)d_out;

    float* ws = (float*)d_ws;
    float* g     = ws;                          // 1M floats (4 MB)
    float* h     = ws + (1 << 20);              // 4M floats (16 MB)
    float* dd    = h + (size_t)BN_TOT * DIM;    // 65536
    float* ss    = dd + BN_TOT;                 // 65536
    float* edi   = ss + BN_TOT;                 // 1024
    float* esi   = edi + N_NODES;               // 1024
    float* nrm   = esi + N_NODES;               // 1024
    int*   tk    = (int*)(nrm + N_NODES);       // 1024*20 ints
    float4* bnp  = (float4*)(tk + N_NODES * TOPK); // 64 float4

    k_build<<<GEMM_BLKS + PREP_BLKS + HSCAL_BLKS, 256, 0, stream>>>(
        data, emb, W_lin, att_i, att_j, att_em_i, att_em_j, gnn_bias,
        g1, b1, m1, v1, g2, b2, m2, v2,
        g, h, dd, ss, edi, esi, nrm, bnp);
    k_topk<<<N_NODES, 256, 0, stream>>>(g, nrm, tk);
    k_main<<<BN_TOT / 4, 256, 0, stream>>>(h, emb, dd, ss, edi, esi, tk, bnp,
                                           outW, outB, out);
}

// Round 5
// 68.008 us; speedup vs baseline: 1.2348x; 1.2304x over previous
//
#include <hip/hip_runtime.h>
#include <hip/hip_bf16.h>

#define N_NODES 1024
#define B_SZ 64
#define F_IN 10
#define DIM 64
#define TOPK 20
#define BN_TOT (B_SZ * N_NODES)   // 65536

#define GT_BLKS 256               // fused cos+topk: 4 rows per block
#define HS_BLKS 4096              // hscal: 16 nodes per block
#define AB_BLKS (GT_BLKS + 1 + HS_BLKS)

// ---- Kernel 1 (k_build): [cos+topk fused] + [bnp fold] + [hscal] via block ranges ----
__global__ __launch_bounds__(256) void k_build(
    const float* __restrict__ data, const float* __restrict__ emb,
    const float* __restrict__ W_lin,
    const float* __restrict__ att_i, const float* __restrict__ att_j,
    const float* __restrict__ att_em_i, const float* __restrict__ att_em_j,
    const float* __restrict__ gnn_bias,
    const float* __restrict__ g1, const float* __restrict__ b1,
    const float* __restrict__ m1, const float* __restrict__ v1,
    const float* __restrict__ g2, const float* __restrict__ b2,
    const float* __restrict__ m2, const float* __restrict__ v2,
    __hip_bfloat16* __restrict__ h, float* __restrict__ ddt,
    float* __restrict__ sst, int* __restrict__ tk, float4* __restrict__ bnp) {
    const int bid = blockIdx.x;
    const int t = threadIdx.x;
    const int lane = t & 63, w = t >> 6;

    if (bid < GT_BLKS) {
        // ---- fused: cos rows [bid*4, bid*4+4) x all 1024 cols + per-row top-20 ----
        __shared__ float As[4][64];
        __shared__ float P[64][65];
        const int r0 = bid * 4;
        As[t >> 6][t & 63] = emb[(r0 + (t >> 6)) * DIM + (t & 63)];
        __syncthreads();
        float av = As[w][lane];
        float nni = av * av;
#pragma unroll
        for (int m = 32; m >= 1; m >>= 1) nni += __shfl_xor(nni, m, 64);
        const float ni = sqrtf(nni);
        float v[16];                      // lane owns columns j = lane + 64p
        for (int p = 0; p < 16; ++p) {
            __syncthreads();
#pragma unroll
            for (int k = 0; k < 16; ++k) {
                int idx = t + k * 256;
                P[idx >> 6][idx & 63] = emb[(p * 64 + (idx >> 6)) * DIM + (idx & 63)];
            }
            __syncthreads();
            float dot = 0.f, nsq = 0.f;
#pragma unroll
            for (int d = 0; d < 64; ++d) {
                float pv = P[lane][d];
                dot = fmaf(As[w][d], pv, dot);
                nsq = fmaf(pv, pv, nsq);
            }
            v[p] = dot / (ni * sqrtf(nsq));
        }
        int* tkr = tk + (r0 + w) * TOPK;
        for (int it = 0; it < TOPK; ++it) {
            float bv = v[0];
            int bp = 0;
#pragma unroll
            for (int p = 1; p < 16; ++p)
                if (v[p] > bv) { bv = v[p]; bp = p; }
            int bidx = lane + bp * 64;
#pragma unroll
            for (int m = 32; m >= 1; m >>= 1) {
                float ov = __shfl_xor(bv, m, 64);
                int oi = __shfl_xor(bidx, m, 64);
                if (ov > bv || (ov == bv && oi < bidx)) { bv = ov; bidx = oi; }
            }
            if (lane == 0) tkr[it] = bidx;
            if ((bidx & 63) == lane) v[bidx >> 6] = -3.0e38f;
        }
        return;
    }

    if (bid == GT_BLKS) {
        if (t < DIM) {
            float a1 = g1[t] * rsqrtf(v1[t] + 1e-5f);
            float c1 = (gnn_bias[t] - m1[t]) * a1 + b1[t];
            float a2 = g2[t] * rsqrtf(v2[t] + 1e-5f);
            float c2 = b2[t] - m2[t] * a2;
            bnp[t] = make_float4(a1, c1, a2, c2);
        }
        return;
    }

    // ---- hscal: h = x@W_lin (bf16 store) + FULLY-FOLDED per-node scalars ----
    {
        const int base = (bid - GT_BLKS - 1) * 16 + w * 4;
        float wl[F_IN];
#pragma unroll
        for (int f = 0; f < F_IN; ++f) wl[f] = W_lin[f * DIM + lane];
        const float ai = att_i[lane], aj = att_j[lane];
        const float aei = att_em_i[lane], aej = att_em_j[lane];
#pragma unroll
        for (int r = 0; r < 4; ++r) {
            const int node = base + r;
            const int i = node & (N_NODES - 1);
            const float ev = emb[i * DIM + lane];
            const float* dp = data + node * F_IN;
            float hv = 0.f;
#pragma unroll
            for (int f = 0; f < F_IN; ++f) hv = fmaf(dp[f], wl[f], hv);
            h[node * DIM + lane] = __float2bfloat16(hv);
            float s1 = fmaf(hv, ai, ev * aei);   // h·att_i + emb·att_em_i
            float s2 = fmaf(hv, aj, ev * aej);   // h·att_j + emb·att_em_j
#pragma unroll
            for (int m = 32; m >= 1; m >>= 1) {
                s1 += __shfl_xor(s1, m, 64);
                s2 += __shfl_xor(s2, m, 64);
            }
            if (lane == 0) { ddt[node] = s1; sst[node] = s2; }
        }
    }
}

// ---- Kernel 2 (k_main): one scalar gather/edge, bf16 h rows (2 lines/gather) ----
__global__ __launch_bounds__(256) void k_main(
    const __hip_bfloat16* __restrict__ h, const float* __restrict__ emb,
    const float* __restrict__ ddt, const float* __restrict__ sst,
    const int* __restrict__ tk, const float4* __restrict__ bnp,
    const float* __restrict__ outW, const float* __restrict__ outB,
    float* __restrict__ out) {
    const int bid = blockIdx.x;
    const int nb = (bid & 7) * 2048 + (bid >> 3);   // XCD swizzle: 8 batches per XCD
    const int w = threadIdx.x >> 6, lane = threadIdx.x & 63;
    const int node = nb * 4 + w;
    const int i = node & (N_NODES - 1);
    const int bbase = node & ~(N_NODES - 1);

    int j = i;
    if (lane < TOPK) j = tk[i * TOPK + lane];

    // single per-edge scalar gather (esi/edi folded into sst/ddt at hscal)
    float sv = 0.f;
    if (lane <= TOPK) sv = sst[bbase + j];
    const float ddv = ddt[node];

    // SGPR row indices -> 21 bf16 row gathers (128 B each)
    const __hip_bfloat16* hb = h + (size_t)bbase * DIM + lane;
    float hvf[TOPK + 1];
#pragma unroll
    for (int k = 0; k < TOPK; ++k) {
        int jk = __builtin_amdgcn_readlane(j, k);
        hvf[k] = __bfloat162float(hb[(size_t)jk * DIM]);
    }
    hvf[TOPK] = __bfloat162float(hb[(size_t)i * DIM]);

    // softmax over <=21 logits
    const bool masked = (lane < TOPK) && (j == i);
    float lg = -3.0e38f;
    if (lane <= TOPK) {
        float l = ddv + sv;
        l = (l > 0.f) ? l : 0.2f * l;              // leaky_relu(0.2)
        lg = masked ? -3.0e38f : l;
    }
    float m = lg;
#pragma unroll
    for (int mm = 16; mm >= 1; mm >>= 1) m = fmaxf(m, __shfl_xor(m, mm, 64));
    float ex = (lane <= TOPK && !masked) ? __expf(lg - m) : 0.f;
    float s = ex;
#pragma unroll
    for (int mm = 16; mm >= 1; mm >>= 1) s += __shfl_xor(s, mm, 64);
    const float alpha = ex / s;

    float agg = 0.f;
#pragma unroll
    for (int k = 0; k <= TOPK; ++k) {
        int ab = __builtin_amdgcn_readlane(__float_as_int(alpha), k);
        agg = fmaf(__int_as_float(ab), hvf[k], agg);
    }

    const float4 p = bnp[lane];
    float x1 = fmaxf(fmaf(agg, p.x, p.y), 0.f);
    float y = x1 * emb[i * DIM + lane];
    float x2 = fmaxf(fmaf(y, p.z, p.w), 0.f);
    float o = x2 * outW[lane];
#pragma unroll
    for (int mm = 32; mm >= 1; mm >>= 1) o += __shfl_xor(o, mm, 64);
    if (lane == 0) out[node] = o + outB[0];
}

extern "C" void kernel_launch(void* const* d_in, const int* in_sizes, int n_in,
                              void* d_out, int out_size, void* d_ws, size_t ws_size,
                              hipStream_t stream) {
    const float* data     = (const float*)d_in[0];
    const float* emb      = (const float*)d_in[1];
    const float* W_lin    = (const float*)d_in[2];
    const float* att_i    = (const float*)d_in[3];
    const float* att_j    = (const float*)d_in[4];
    const float* att_em_i = (const float*)d_in[5];
    const float* att_em_j = (const float*)d_in[6];
    const float* gnn_bias = (const float*)d_in[7];
    const float* g1 = (const float*)d_in[8];
    const float* b1 = (const float*)d_in[9];
    const float* m1 = (const float*)d_in[10];
    const float* v1 = (const float*)d_in[11];
    const float* g2 = (const float*)d_in[12];
    const float* b2 = (const float*)d_in[13];
    const float* m2 = (const float*)d_in[14];
    const float* v2 = (const float*)d_in[15];
    const float* outW = (const float*)d_in[16];
    const float* outB = (const float*)d_in[17];
    float* out = (float*)d_out;

    char* ws = (char*)d_ws;
    __hip_bfloat16* h = (__hip_bfloat16*)ws;                 // 8 MB
    float* ddt  = (float*)(ws + (size_t)8 * 1024 * 1024);    // 256 KB
    float* sst  = ddt + BN_TOT;                              // 256 KB
    int*   tk   = (int*)(sst + BN_TOT);                      // 80 KB
    float4* bnp = (float4*)(tk + N_NODES * TOPK);            // 1 KB

    k_build<<<AB_BLKS, 256, 0, stream>>>(
        data, emb, W_lin, att_i, att_j, att_em_i, att_em_j, gnn_bias,
        g1, b1, m1, v1, g2, b2, m2, v2,
        h, ddt, sst, tk, bnp);
    k_main<<<BN_TOT / 4, 256, 0, stream>>>(h, emb, ddt, sst, tk, bnp,
                                           outW, outB, out);
}